// Round 1
// baseline (1067.715 us; speedup 1.0000x reference)
//
#include <hip/hip_runtime.h>

// WaveGC wavelet conv, fp32 baseline.
// Pipeline:
//  1. P[t]  = x @ W_gcn[t]                        (batched sgemm, 2.4 GF)
//  2. F[t]  = V diag(s_t) V^T  (symmetric; upper-tri blocks + mirror, 68.7 GF/2)
//  3. G[t]  = threshold(F[t] row-scaled by 1/rownorm)   [= Fm^T by symmetry]
//  4. H[t]  = relu(G[t] @ P[t] + b_gcn[t])        (batched sgemm, 12.9 GF)
//  5. comb[:, t*192:(t+1)*192] = G[t] @ H[t]      (batched sgemm, 12.9 GF)
//  6. out   = relu(comb @ fusion_W + fusion_b)    (sgemm, 2.4 GF)
// ws layout (floats): F 4*2048*2048 | P 4*2048*192 | H 4*2048*192 | comb 2048*768
// total ws = 86 MB.

#define NN 2048

// ---------------------------------------------------------------------------
// Stage 2: F[t][i][j] = sum_k V[i][k] * s[t][k] * V[j][k], fused over 4 t.
// 64x64 block tile, 256 threads, 4x4 micro-tile x 4 t accumulators.
// Only upper-triangular block pairs (bi<=bj); mirror-write the transpose.
// ---------------------------------------------------------------------------
__global__ __launch_bounds__(256, 2)
void wave_filters_kernel(const float* __restrict__ V,
                         const float* __restrict__ sig,  // [N][4] : sig[k*4+t]
                         float* __restrict__ F)          // [4][N][N]
{
    const int N = NN;
    __shared__ float As[16][68];   // As[k][i] = V[i0+i][k0+k]  (+4 pad: 16B-aligned rows, 2-way max)
    __shared__ float Bs[16][68];   // Bs[k][j] = V[j0+j][k0+k]
    __shared__ float Ss[16][4];    // Ss[k][t]

    // decode upper-triangular pair (bi <= bj), 32x33/2 = 528 blocks
    int rem = blockIdx.x, bi = 0, span = 32;
    while (rem >= span) { rem -= span; ++bi; --span; }
    int bj = bi + rem;
    int i0 = bi * 64, j0 = bj * 64;

    int tid = threadIdx.x;
    int tx = tid & 15, ty = tid >> 4;      // tx -> j (coalesced stores), ty -> i
    int ar = tid >> 2, ac = (tid & 3) * 4; // staging: 4 threads per row, float4 each

    float acc[4][4][4];
    #pragma unroll
    for (int t = 0; t < 4; ++t)
        #pragma unroll
        for (int i = 0; i < 4; ++i)
            #pragma unroll
            for (int j = 0; j < 4; ++j) acc[t][i][j] = 0.f;

    for (int k0 = 0; k0 < N; k0 += 16) {
        float4 av = *(const float4*)(V + (long)(i0 + ar) * N + k0 + ac);
        float4 bv = *(const float4*)(V + (long)(j0 + ar) * N + k0 + ac);
        As[ac + 0][ar] = av.x; As[ac + 1][ar] = av.y;
        As[ac + 2][ar] = av.z; As[ac + 3][ar] = av.w;
        Bs[ac + 0][ar] = bv.x; Bs[ac + 1][ar] = bv.y;
        Bs[ac + 2][ar] = bv.z; Bs[ac + 3][ar] = bv.w;
        if (tid < 16)
            *(float4*)&Ss[tid][0] = *(const float4*)(sig + (long)(k0 + tid) * 4);
        __syncthreads();

        #pragma unroll
        for (int kk = 0; kk < 16; ++kk) {
            float a[4], b[4], s[4];
            *(float4*)a = *(const float4*)&As[kk][ty * 4];
            *(float4*)b = *(const float4*)&Bs[kk][tx * 4];
            *(float4*)s = *(const float4*)&Ss[kk][0];   // same-address broadcast
            #pragma unroll
            for (int i = 0; i < 4; ++i)
                #pragma unroll
                for (int j = 0; j < 4; ++j) {
                    float p = a[i] * b[j];
                    acc[0][i][j] = fmaf(p, s[0], acc[0][i][j]);
                    acc[1][i][j] = fmaf(p, s[1], acc[1][i][j]);
                    acc[2][i][j] = fmaf(p, s[2], acc[2][i][j]);
                    acc[3][i][j] = fmaf(p, s[3], acc[3][i][j]);
                }
        }
        __syncthreads();
    }

    #pragma unroll
    for (int t = 0; t < 4; ++t) {
        #pragma unroll
        for (int i = 0; i < 4; ++i) {
            long row = i0 + ty * 4 + i;
            float4 v = make_float4(acc[t][i][0], acc[t][i][1], acc[t][i][2], acc[t][i][3]);
            *(float4*)(F + ((long)t * N + row) * N + j0 + tx * 4) = v;
        }
        if (bi != bj) {
            #pragma unroll
            for (int j = 0; j < 4; ++j) {
                long row = j0 + tx * 4 + j;
                float4 v = make_float4(acc[t][0][j], acc[t][1][j], acc[t][2][j], acc[t][3][j]);
                *(float4*)(F + ((long)t * N + row) * N + i0 + ty * 4) = v;
            }
        }
    }
}

// ---------------------------------------------------------------------------
// Stage 3: in-place  G[t][j][:] = thresh( F[t][j][:] / max(||F[t][j][:]||, 1e-12) )
// (row norm == reference's column norm because F is symmetric bitwise here)
// ---------------------------------------------------------------------------
__global__ __launch_bounds__(256)
void norm_scale_kernel(float* __restrict__ F)
{
    const int N = NN;
    int row = blockIdx.x, t = blockIdx.y;
    float* R = F + ((long)t * N + row) * N;
    int tid = threadIdx.x;

    float ss = 0.f;
    #pragma unroll
    for (int c = tid * 4; c < N; c += 1024) {
        float4 v = *(const float4*)(R + c);
        ss += v.x * v.x + v.y * v.y + v.z * v.z + v.w * v.w;
    }
    #pragma unroll
    for (int off = 32; off > 0; off >>= 1) ss += __shfl_down(ss, off, 64);

    __shared__ float partial[4];
    __shared__ float s_inv;
    if ((tid & 63) == 0) partial[tid >> 6] = ss;
    __syncthreads();
    if (tid == 0) {
        float tot = partial[0] + partial[1] + partial[2] + partial[3];
        s_inv = 1.f / fmaxf(sqrtf(tot), 1e-12f);
    }
    __syncthreads();
    float inv = s_inv;

    #pragma unroll
    for (int c = tid * 4; c < N; c += 1024) {
        float4 v = *(const float4*)(R + c);
        v.x *= inv; v.y *= inv; v.z *= inv; v.w *= inv;
        v.x = (fabsf(v.x) > 1e-4f) ? v.x : 0.f;
        v.y = (fabsf(v.y) > 1e-4f) ? v.y : 0.f;
        v.z = (fabsf(v.z) > 1e-4f) ? v.z : 0.f;
        v.w = (fabsf(v.w) > 1e-4f) ? v.w : 0.f;
        *(float4*)(R + c) = v;
    }
}

// ---------------------------------------------------------------------------
// Generic batched SGEMM: C[b] = [relu]( A[b] @ B[b] [+ bias[b]] )
// A [M][K] row-major, B [K][N] row-major, C rows have leading dim ldc.
// 64x64 block tile, BK=16, 256 threads, 4x4 micro-tile.
// Requires M%64==0, N%64==0, K%16==0 (true for all call sites).
// ---------------------------------------------------------------------------
template<bool RELU, bool HASBIAS>
__global__ __launch_bounds__(256)
void sgemm_kernel(const float* __restrict__ A, const float* __restrict__ B,
                  float* __restrict__ C, const float* __restrict__ bias,
                  int M, int N, int K,
                  long strideA, long strideB, long strideC, int ldc, int biasStride)
{
    __shared__ float As[16][68];   // As[k][m] (transposed stage)
    __shared__ float Bs[16][68];   // Bs[k][n]

    int b = blockIdx.z;
    A += (long)b * strideA;
    B += (long)b * strideB;
    C += (long)b * strideC;

    int bm = blockIdx.y * 64, bn = blockIdx.x * 64;
    int tid = threadIdx.x;
    int tx = tid & 15, ty = tid >> 4;
    int ar = tid >> 2, ac = (tid & 3) * 4;   // A stage: row bm+ar, k-cols ac..ac+3
    int br = tid >> 4, bc = (tid & 15) * 4;  // B stage: row k0+br, n-cols bc..bc+3

    float acc[4][4];
    #pragma unroll
    for (int i = 0; i < 4; ++i)
        #pragma unroll
        for (int j = 0; j < 4; ++j) acc[i][j] = 0.f;

    for (int k0 = 0; k0 < K; k0 += 16) {
        float4 av = *(const float4*)(A + (long)(bm + ar) * K + k0 + ac);
        As[ac + 0][ar] = av.x; As[ac + 1][ar] = av.y;
        As[ac + 2][ar] = av.z; As[ac + 3][ar] = av.w;
        *(float4*)&Bs[br][bc] = *(const float4*)(B + (long)(k0 + br) * N + bn + bc);
        __syncthreads();

        #pragma unroll
        for (int kk = 0; kk < 16; ++kk) {
            float a[4], v[4];
            *(float4*)a = *(const float4*)&As[kk][ty * 4];
            *(float4*)v = *(const float4*)&Bs[kk][tx * 4];
            #pragma unroll
            for (int i = 0; i < 4; ++i)
                #pragma unroll
                for (int j = 0; j < 4; ++j)
                    acc[i][j] = fmaf(a[i], v[j], acc[i][j]);
        }
        __syncthreads();
    }

    int col = bn + tx * 4;
    #pragma unroll
    for (int i = 0; i < 4; ++i) {
        long row = bm + ty * 4 + i;
        float4 v = make_float4(acc[i][0], acc[i][1], acc[i][2], acc[i][3]);
        if (HASBIAS) {
            float4 bb = *(const float4*)(bias + (long)b * biasStride + col);
            v.x += bb.x; v.y += bb.y; v.z += bb.z; v.w += bb.w;
        }
        if (RELU) {
            v.x = fmaxf(v.x, 0.f); v.y = fmaxf(v.y, 0.f);
            v.z = fmaxf(v.z, 0.f); v.w = fmaxf(v.w, 0.f);
        }
        *(float4*)(C + row * ldc + col) = v;
    }
}

// ---------------------------------------------------------------------------
extern "C" void kernel_launch(void* const* d_in, const int* in_sizes, int n_in,
                              void* d_out, int out_size, void* d_ws, size_t ws_size,
                              hipStream_t stream)
{
    const float* x   = (const float*)d_in[0];  // [2048][768]
    const float* evc = (const float*)d_in[1];  // [2048][2048]
    const float* sig = (const float*)d_in[2];  // [1][2048][4] -> [k][t]
    const float* Wg  = (const float*)d_in[3];  // [4][768][192]
    const float* bg  = (const float*)d_in[4];  // [4][192]
    const float* Wf  = (const float*)d_in[5];  // [768][768]
    const float* bf  = (const float*)d_in[6];  // [768]
    float* out = (float*)d_out;                // [2048][768]

    float* F    = (float*)d_ws;                        // [4][2048][2048]
    float* P    = F + (size_t)4 * NN * NN;             // [4][2048][192]
    float* H    = P + (size_t)4 * NN * 192;            // [4][2048][192]
    float* comb = H + (size_t)4 * NN * 192;            // [2048][768]

    // 1. P[t] = x @ W_gcn[t]
    sgemm_kernel<false, false><<<dim3(3, 32, 4), 256, 0, stream>>>(
        x, Wg, P, nullptr, 2048, 192, 768,
        0L, (long)768 * 192, (long)2048 * 192, 192, 0);

    // 2. F[t] = V diag(s_t) V^T  (symmetric, fused over t)
    wave_filters_kernel<<<dim3(528), 256, 0, stream>>>(evc, sig, F);

    // 3. G[t] = threshold(row-normalized F[t])  (in place; G == Fm^T)
    norm_scale_kernel<<<dim3(2048, 4), 256, 0, stream>>>(F);

    // 4. H[t] = relu(G[t] @ P[t] + b_gcn[t])
    sgemm_kernel<true, true><<<dim3(3, 32, 4), 256, 0, stream>>>(
        F, P, H, bg, 2048, 192, 2048,
        (long)NN * NN, (long)2048 * 192, (long)2048 * 192, 192, 192);

    // 5. comb[:, t*192:(t+1)*192] = G[t] @ H[t]
    sgemm_kernel<false, false><<<dim3(3, 32, 4), 256, 0, stream>>>(
        F, H, comb, nullptr, 2048, 192, 2048,
        (long)NN * NN, (long)2048 * 192, 192L, 768, 0);

    // 6. out = relu(comb @ fusion_W + fusion_b)
    sgemm_kernel<true, true><<<dim3(12, 32, 1), 256, 0, stream>>>(
        comb, Wf, out, bf, 2048, 768, 768,
        0L, 0L, 0L, 768, 768);
}

// Round 2
// 731.695 us; speedup vs baseline: 1.4592x; 1.4592x over previous
//
#include <hip/hip_runtime.h>

// WaveGC wavelet conv. Round 2: F-stage on MFMA (split-bf16, fp32-class accuracy).
//
// F_t = (V diag(sqrt(s_t))) (V diag(sqrt(s_t)))^T  = A_t A_t^T
// A_t split to bf16 hi+lo; A*A^T = Ah*Ah^T + Ah*Al^T + Al*Ah^T (drop lo*lo, ~2^-18 rel).
//
// ws layout (bytes):
//   F    [4][2048][2048] f32      @ 0          (67.1 MB)     lives whole call
//   A_hi [2048][2048] bf16        @ 67.1MB     (8.4 MB)  \   stage-2 only; region
//   A_lo [2048][2048] bf16        @ 75.5MB     (8.4 MB)  /   reused afterwards by:
//   P    [4][2048][192] f32       @ 67.1MB     (6.3 MB)
//   H    [4][2048][192] f32       @ 73.4MB     (6.3 MB)
//   comb [2048][768] f32          @ 79.7MB     (6.3 MB)
// peak 86.0 MB (same footprint as round 1, which fit).

#define NN 2048

typedef short   bf16x8 __attribute__((ext_vector_type(8)));
typedef float   f32x4  __attribute__((ext_vector_type(4)));

// ---------------------------------------------------------------------------
// Prep: A_t[i][k] = V[i][k] * sqrt(s_t[k]), split into bf16 hi/lo (RNE).
// ---------------------------------------------------------------------------
__device__ inline unsigned short bf16_rne(float f) {
    unsigned int u = __float_as_uint(f);
    u += 0x7fffu + ((u >> 16) & 1u);
    return (unsigned short)(u >> 16);
}

__global__ __launch_bounds__(256)
void prep_kernel(const float* __restrict__ V, const float* __restrict__ sig, int t,
                 unsigned short* __restrict__ Ah, unsigned short* __restrict__ Al)
{
    long idx = ((long)blockIdx.x * 256 + threadIdx.x) * 4;
    int k = (int)(idx & (NN - 1));
    float4 v = *(const float4*)(V + idx);
    float a[4];
    a[0] = v.x * sqrtf(sig[(k + 0) * 4 + t]);
    a[1] = v.y * sqrtf(sig[(k + 1) * 4 + t]);
    a[2] = v.z * sqrtf(sig[(k + 2) * 4 + t]);
    a[3] = v.w * sqrtf(sig[(k + 3) * 4 + t]);
    ushort4 hi, lo;
    unsigned short h;
    h = bf16_rne(a[0]); hi.x = h; lo.x = bf16_rne(a[0] - __uint_as_float((unsigned)h << 16));
    h = bf16_rne(a[1]); hi.y = h; lo.y = bf16_rne(a[1] - __uint_as_float((unsigned)h << 16));
    h = bf16_rne(a[2]); hi.z = h; lo.z = bf16_rne(a[2] - __uint_as_float((unsigned)h << 16));
    h = bf16_rne(a[3]); hi.w = h; lo.w = bf16_rne(a[3] - __uint_as_float((unsigned)h << 16));
    *(ushort4*)(Ah + idx) = hi;
    *(ushort4*)(Al + idx) = lo;
}

// ---------------------------------------------------------------------------
// Stage 2 (MFMA): F_t = A_t A_t^T.  128x128 block tile, 4 waves, each wave a
// 64x64 quadrant of 4x4 16x16 frags. BK=64 (two k32 mfma steps).
// LDS tiles XOR-swizzled (kgroup ^= row&7) -> conflict-free ds_read_b128.
// A frag: m=lane&15, k=(lane>>4)*8+j  |  B frag: n=lane&15, k=(lane>>4)*8+j
// (both = 8 consecutive bf16 from a row of A_t; B side uses rows j0.. = A^T)
// C frag: col=lane&15, row=(lane>>4)*4+reg.
// ---------------------------------------------------------------------------
__global__ __launch_bounds__(256, 2)
void mfma_filter_kernel(const unsigned short* __restrict__ Ah,
                        const unsigned short* __restrict__ Al,
                        float* __restrict__ Fout)
{
    const int N = NN;
    __shared__ unsigned short sAh[128 * 64];
    __shared__ unsigned short sAl[128 * 64];
    __shared__ unsigned short sBh[128 * 64];
    __shared__ unsigned short sBl[128 * 64];

    int i0 = blockIdx.y * 128, j0 = blockIdx.x * 128;
    int tid = threadIdx.x;
    int lane = tid & 63, w = tid >> 6;
    int wr = (w & 1) * 64, wc = (w >> 1) * 64;
    int q = lane >> 4, r15 = lane & 15;

    f32x4 acc[4][4];
    #pragma unroll
    for (int i = 0; i < 4; ++i)
        #pragma unroll
        for (int j = 0; j < 4; ++j)
            acc[i][j] = (f32x4){0.f, 0.f, 0.f, 0.f};

    for (int k0 = 0; k0 < N; k0 += 64) {
        // stage 4 tiles: 128 rows x 64 bf16 each; thread does 4 chunks/array
        #pragma unroll
        for (int p = 0; p < 4; ++p) {
            int c = p * 256 + tid;
            int row = c >> 3, g = c & 7;
            int dst = row * 64 + ((g ^ (row & 7)) * 8);
            long offA = (long)(i0 + row) * N + k0 + g * 8;
            long offB = (long)(j0 + row) * N + k0 + g * 8;
            uint4 vah = *(const uint4*)(Ah + offA);
            uint4 val = *(const uint4*)(Al + offA);
            uint4 vbh = *(const uint4*)(Ah + offB);
            uint4 vbl = *(const uint4*)(Al + offB);
            *(uint4*)&sAh[dst] = vah;
            *(uint4*)&sAl[dst] = val;
            *(uint4*)&sBh[dst] = vbh;
            *(uint4*)&sBl[dst] = vbl;
        }
        __syncthreads();

        #pragma unroll
        for (int s = 0; s < 2; ++s) {
            int g = s * 4 + q;
            bf16x8 fAh[4], fAl[4], fBh[4], fBl[4];
            #pragma unroll
            for (int f = 0; f < 4; ++f) {
                int ra = wr + f * 16 + r15;
                int aa = ra * 64 + ((g ^ (ra & 7)) * 8);
                fAh[f] = *(const bf16x8*)&sAh[aa];
                fAl[f] = *(const bf16x8*)&sAl[aa];
                int rb = wc + f * 16 + r15;
                int ab = rb * 64 + ((g ^ (rb & 7)) * 8);
                fBh[f] = *(const bf16x8*)&sBh[ab];
                fBl[f] = *(const bf16x8*)&sBl[ab];
            }
            #pragma unroll
            for (int fi = 0; fi < 4; ++fi)
                #pragma unroll
                for (int fj = 0; fj < 4; ++fj) {
                    acc[fi][fj] = __builtin_amdgcn_mfma_f32_16x16x32_bf16(
                        fAh[fi], fBh[fj], acc[fi][fj], 0, 0, 0);
                    acc[fi][fj] = __builtin_amdgcn_mfma_f32_16x16x32_bf16(
                        fAh[fi], fBl[fj], acc[fi][fj], 0, 0, 0);
                    acc[fi][fj] = __builtin_amdgcn_mfma_f32_16x16x32_bf16(
                        fAl[fi], fBh[fj], acc[fi][fj], 0, 0, 0);
                }
        }
        __syncthreads();
    }

    #pragma unroll
    for (int fi = 0; fi < 4; ++fi)
        #pragma unroll
        for (int fj = 0; fj < 4; ++fj) {
            int col = j0 + wc + fj * 16 + r15;
            #pragma unroll
            for (int r = 0; r < 4; ++r) {
                int row = i0 + wr + fi * 16 + q * 4 + r;
                Fout[(long)row * N + col] = acc[fi][fj][r];
            }
        }
}

// ---------------------------------------------------------------------------
// Stage 3: in-place  G[t][j][:] = thresh( F[t][j][:] / max(||row||, 1e-12) )
// (F is symmetric to ~1e-7 rel; row norm == reference col norm)
// ---------------------------------------------------------------------------
__global__ __launch_bounds__(256)
void norm_scale_kernel(float* __restrict__ F)
{
    const int N = NN;
    int row = blockIdx.x, t = blockIdx.y;
    float* R = F + ((long)t * N + row) * N;
    int tid = threadIdx.x;

    float ss = 0.f;
    #pragma unroll
    for (int c = tid * 4; c < N; c += 1024) {
        float4 v = *(const float4*)(R + c);
        ss += v.x * v.x + v.y * v.y + v.z * v.z + v.w * v.w;
    }
    #pragma unroll
    for (int off = 32; off > 0; off >>= 1) ss += __shfl_down(ss, off, 64);

    __shared__ float partial[4];
    __shared__ float s_inv;
    if ((tid & 63) == 0) partial[tid >> 6] = ss;
    __syncthreads();
    if (tid == 0) {
        float tot = partial[0] + partial[1] + partial[2] + partial[3];
        s_inv = 1.f / fmaxf(sqrtf(tot), 1e-12f);
    }
    __syncthreads();
    float inv = s_inv;

    #pragma unroll
    for (int c = tid * 4; c < N; c += 1024) {
        float4 v = *(const float4*)(R + c);
        v.x *= inv; v.y *= inv; v.z *= inv; v.w *= inv;
        v.x = (fabsf(v.x) > 1e-4f) ? v.x : 0.f;
        v.y = (fabsf(v.y) > 1e-4f) ? v.y : 0.f;
        v.z = (fabsf(v.z) > 1e-4f) ? v.z : 0.f;
        v.w = (fabsf(v.w) > 1e-4f) ? v.w : 0.f;
        *(float4*)(R + c) = v;
    }
}

// ---------------------------------------------------------------------------
// Generic batched SGEMM (fp32 VALU): C[b] = [relu]( A[b] @ B[b] [+ bias[b]] )
// ---------------------------------------------------------------------------
template<bool RELU, bool HASBIAS>
__global__ __launch_bounds__(256)
void sgemm_kernel(const float* __restrict__ A, const float* __restrict__ B,
                  float* __restrict__ C, const float* __restrict__ bias,
                  int M, int N, int K,
                  long strideA, long strideB, long strideC, int ldc, int biasStride)
{
    __shared__ float As[16][68];
    __shared__ float Bs[16][68];

    int b = blockIdx.z;
    A += (long)b * strideA;
    B += (long)b * strideB;
    C += (long)b * strideC;

    int bm = blockIdx.y * 64, bn = blockIdx.x * 64;
    int tid = threadIdx.x;
    int tx = tid & 15, ty = tid >> 4;
    int ar = tid >> 2, ac = (tid & 3) * 4;
    int br = tid >> 4, bc = (tid & 15) * 4;

    float acc[4][4];
    #pragma unroll
    for (int i = 0; i < 4; ++i)
        #pragma unroll
        for (int j = 0; j < 4; ++j) acc[i][j] = 0.f;

    for (int k0 = 0; k0 < K; k0 += 16) {
        float4 av = *(const float4*)(A + (long)(bm + ar) * K + k0 + ac);
        As[ac + 0][ar] = av.x; As[ac + 1][ar] = av.y;
        As[ac + 2][ar] = av.z; As[ac + 3][ar] = av.w;
        *(float4*)&Bs[br][bc] = *(const float4*)(B + (long)(k0 + br) * N + bn + bc);
        __syncthreads();

        #pragma unroll
        for (int kk = 0; kk < 16; ++kk) {
            float a[4], v[4];
            *(float4*)a = *(const float4*)&As[kk][ty * 4];
            *(float4*)v = *(const float4*)&Bs[kk][tx * 4];
            #pragma unroll
            for (int i = 0; i < 4; ++i)
                #pragma unroll
                for (int j = 0; j < 4; ++j)
                    acc[i][j] = fmaf(a[i], v[j], acc[i][j]);
        }
        __syncthreads();
    }

    int col = bn + tx * 4;
    #pragma unroll
    for (int i = 0; i < 4; ++i) {
        long row = bm + ty * 4 + i;
        float4 v = make_float4(acc[i][0], acc[i][1], acc[i][2], acc[i][3]);
        if (HASBIAS) {
            float4 bb = *(const float4*)(bias + (long)b * biasStride + col);
            v.x += bb.x; v.y += bb.y; v.z += bb.z; v.w += bb.w;
        }
        if (RELU) {
            v.x = fmaxf(v.x, 0.f); v.y = fmaxf(v.y, 0.f);
            v.z = fmaxf(v.z, 0.f); v.w = fmaxf(v.w, 0.f);
        }
        *(float4*)(C + row * ldc + col) = v;
    }
}

// ---------------------------------------------------------------------------
extern "C" void kernel_launch(void* const* d_in, const int* in_sizes, int n_in,
                              void* d_out, int out_size, void* d_ws, size_t ws_size,
                              hipStream_t stream)
{
    const float* x   = (const float*)d_in[0];  // [2048][768]
    const float* evc = (const float*)d_in[1];  // [2048][2048]
    const float* sig = (const float*)d_in[2];  // [1][2048][4] -> sig[k*4+t]
    const float* Wg  = (const float*)d_in[3];  // [4][768][192]
    const float* bg  = (const float*)d_in[4];  // [4][192]
    const float* Wf  = (const float*)d_in[5];  // [768][768]
    const float* bf  = (const float*)d_in[6];  // [768]
    float* out = (float*)d_out;                // [2048][768]

    float* F = (float*)d_ws;                              // [4][N][N] f32
    unsigned short* Ahi = (unsigned short*)(F + (size_t)4 * NN * NN);
    unsigned short* Alo = Ahi + (size_t)NN * NN;
    // after stage 2, this region is reused:
    float* P    = (float*)Ahi;                            // [4][2048][192]
    float* H    = P + (size_t)4 * NN * 192;               // [4][2048][192]
    float* comb = H + (size_t)4 * NN * 192;               // [2048][768]

    // Stage 2: per-t prep + MFMA filter (F[t] = A_t A_t^T)
    for (int t = 0; t < 4; ++t) {
        prep_kernel<<<dim3(NN * NN / 1024), 256, 0, stream>>>(evc, sig, t, Ahi, Alo);
        mfma_filter_kernel<<<dim3(16, 16), 256, 0, stream>>>(
            Ahi, Alo, F + (size_t)t * NN * NN);
    }

    // Stage 3: G[t] = threshold(row-normalized F[t])  (in place)
    norm_scale_kernel<<<dim3(NN, 4), 256, 0, stream>>>(F);

    // Stage 1 (moved after stage 2 — P overwrites the A_t region): P[t] = x @ W_gcn[t]
    sgemm_kernel<false, false><<<dim3(3, 32, 4), 256, 0, stream>>>(
        x, Wg, P, nullptr, 2048, 192, 768,
        0L, (long)768 * 192, (long)2048 * 192, 192, 0);

    // Stage 4: H[t] = relu(G[t] @ P[t] + b_gcn[t])
    sgemm_kernel<true, true><<<dim3(3, 32, 4), 256, 0, stream>>>(
        F, P, H, bg, 2048, 192, 2048,
        (long)NN * NN, (long)2048 * 192, (long)2048 * 192, 192, 192);

    // Stage 5: comb[:, t*192:(t+1)*192] = G[t] @ H[t]
    sgemm_kernel<false, false><<<dim3(3, 32, 4), 256, 0, stream>>>(
        F, H, comb, nullptr, 2048, 192, 2048,
        (long)NN * NN, (long)2048 * 192, 192L, 768, 0);

    // Stage 6: out = relu(comb @ fusion_W + fusion_b)
    sgemm_kernel<true, true><<<dim3(12, 32, 1), 256, 0, stream>>>(
        comb, Wf, out, bf, 2048, 768, 768,
        0L, 0L, 0L, 768, 768);
}

// Round 3
// 622.016 us; speedup vs baseline: 1.7165x; 1.1763x over previous
//
#include <hip/hip_runtime.h>

// WaveGC wavelet conv. Round 3: whole pipeline on split-bf16 MFMA NT-GEMMs.
//
// NT-GEMM: C[i][j] = sum_k A[i][k]*B[j][k], A [M][K], B [N][K] row-major.
//  filter: F_t = NT(A_t, A_t) + fused row-sumsq            (A_t = V*sqrt(s_t))
//  gmask : G_t = resplit(thresh(F_t * inv_row))  in place
//  st1   : PT  = NT(WgT_pad, x)            [192(n) x 2048(m)]
//  st4   : HT  = relu(NT(PT, G) + bg)      [192(n) x 2048(m)]
//  st5   : comb= NT(G, HT)                 [2048(m) x 192(n)] -> cols t*192..
//  st6   : out = relu(NT(comb, WfT) + bf)  [2048 x 768] fp32
//
// ws overlay (bytes, peak 84.0 MB <= proven 86.0 MB):
//  [0, 33.55M)      Fhi -> Ghi (in place)        | after st5: WfT hi/lo @0 (2.4M)
//  [33.55M, 67.11M) Flo -> Glo
//  R = 67.11M, 16.78M region:
//    phase filter: Ah (8.39M) | Al (8.39M)
//    phase st1   : xh/xl (6.29M) | WgT hi/lo (3.15M) | PT hi/lo (6.29M)
//    phase st4/5 : HT hi/lo (6.29M) @R+0            | comb hi/lo (6.29M) @R+9.44M
//  tail @ 83.89M: rowsumsq 32K | inv 32K | bg_pad 4K

#define NN 2048

typedef short bf16x8 __attribute__((ext_vector_type(8)));
typedef float f32x4  __attribute__((ext_vector_type(4)));

__device__ inline unsigned short bf16_rne(float f) {
    unsigned int u = __float_as_uint(f);
    u += 0x7fffu + ((u >> 16) & 1u);
    return (unsigned short)(u >> 16);
}
__device__ inline float bf16_f(unsigned short h) {
    return __uint_as_float((unsigned)h << 16);
}

// ---------------------------------------------------------------------------
// Generic split-bf16 NT MFMA GEMM. 128x128 block, BK=64, 4 waves (64x64 each).
// XOR-swizzled LDS; 3-mfma split (hh, hl, lh) per fragment pair.
// BIASM: 0 none, 1 per-row (bias[i]), 2 per-col (bias[j]).
// ---------------------------------------------------------------------------
template<int BIASM, bool RELU, bool OUTF32, bool SUMSQ>
__global__ __launch_bounds__(256, 2)
void nt_gemm(const unsigned short* __restrict__ Ah, const unsigned short* __restrict__ Al,
             const unsigned short* __restrict__ Bh, const unsigned short* __restrict__ Bl,
             unsigned short* __restrict__ Ch, unsigned short* __restrict__ Cl,
             float* __restrict__ Cf,
             const float* __restrict__ bias, float* __restrict__ sumsq,
             int K, int a_rows, int b_rows, int i_valid, int j_valid, int ldc,
             long sA, long sB, long sC, int sBias)
{
    __shared__ unsigned short sAh[128 * 64];
    __shared__ unsigned short sAl[128 * 64];
    __shared__ unsigned short sBh[128 * 64];
    __shared__ unsigned short sBl[128 * 64];

    int z = blockIdx.z;
    Ah += z * sA; Al += z * sA;
    Bh += z * sB; Bl += z * sB;
    if (OUTF32) Cf += z * sC; else { Ch += z * sC; Cl += z * sC; }
    if (BIASM)  bias += (long)z * sBias;

    int i0 = blockIdx.y * 128, j0 = blockIdx.x * 128;
    int tid = threadIdx.x;
    int lane = tid & 63, w = tid >> 6;
    int wr = (w & 1) * 64, wc = (w >> 1) * 64;
    int q = lane >> 4, r15 = lane & 15;

    f32x4 acc[4][4];
    #pragma unroll
    for (int i = 0; i < 4; ++i)
        #pragma unroll
        for (int j = 0; j < 4; ++j)
            acc[i][j] = (f32x4){0.f, 0.f, 0.f, 0.f};

    for (int k0 = 0; k0 < K; k0 += 64) {
        #pragma unroll
        for (int p = 0; p < 4; ++p) {
            int c = p * 256 + tid;
            int row = c >> 3, g = c & 7;
            int dst = row * 64 + ((g ^ (row & 7)) * 8);
            int ra = min(i0 + row, a_rows - 1);
            int rb = min(j0 + row, b_rows - 1);
            long offA = (long)ra * K + k0 + g * 8;
            long offB = (long)rb * K + k0 + g * 8;
            *(uint4*)&sAh[dst] = *(const uint4*)(Ah + offA);
            *(uint4*)&sAl[dst] = *(const uint4*)(Al + offA);
            *(uint4*)&sBh[dst] = *(const uint4*)(Bh + offB);
            *(uint4*)&sBl[dst] = *(const uint4*)(Bl + offB);
        }
        __syncthreads();

        #pragma unroll
        for (int s = 0; s < 2; ++s) {
            int g = s * 4 + q;
            bf16x8 fAh[4], fAl[4], fBh[4], fBl[4];
            #pragma unroll
            for (int f = 0; f < 4; ++f) {
                int ra = wr + f * 16 + r15;
                int aa = ra * 64 + ((g ^ (ra & 7)) * 8);
                fAh[f] = *(const bf16x8*)&sAh[aa];
                fAl[f] = *(const bf16x8*)&sAl[aa];
                int rb = wc + f * 16 + r15;
                int ab = rb * 64 + ((g ^ (rb & 7)) * 8);
                fBh[f] = *(const bf16x8*)&sBh[ab];
                fBl[f] = *(const bf16x8*)&sBl[ab];
            }
            #pragma unroll
            for (int fi = 0; fi < 4; ++fi)
                #pragma unroll
                for (int fj = 0; fj < 4; ++fj) {
                    acc[fi][fj] = __builtin_amdgcn_mfma_f32_16x16x32_bf16(
                        fAh[fi], fBh[fj], acc[fi][fj], 0, 0, 0);
                    acc[fi][fj] = __builtin_amdgcn_mfma_f32_16x16x32_bf16(
                        fAh[fi], fBl[fj], acc[fi][fj], 0, 0, 0);
                    acc[fi][fj] = __builtin_amdgcn_mfma_f32_16x16x32_bf16(
                        fAl[fi], fBh[fj], acc[fi][fj], 0, 0, 0);
                }
        }
        __syncthreads();
    }

    if (SUMSQ) {
        #pragma unroll
        for (int fi = 0; fi < 4; ++fi)
            #pragma unroll
            for (int r = 0; r < 4; ++r) {
                float s = 0.f;
                #pragma unroll
                for (int fj = 0; fj < 4; ++fj) {
                    float v = acc[fi][fj][r];
                    s += v * v;
                }
                s += __shfl_xor(s, 1); s += __shfl_xor(s, 2);
                s += __shfl_xor(s, 4); s += __shfl_xor(s, 8);
                if (r15 == 0)
                    atomicAdd(&sumsq[i0 + wr + fi * 16 + q * 4 + r], s);
            }
    }

    #pragma unroll
    for (int fi = 0; fi < 4; ++fi)
        #pragma unroll
        for (int fj = 0; fj < 4; ++fj) {
            int col = j0 + wc + fj * 16 + r15;
            if (col >= j_valid) continue;
            #pragma unroll
            for (int r = 0; r < 4; ++r) {
                int row = i0 + wr + fi * 16 + q * 4 + r;
                if (row >= i_valid) continue;
                float v = acc[fi][fj][r];
                if (BIASM == 1) v += bias[row];
                if (BIASM == 2) v += bias[col];
                if (RELU) v = fmaxf(v, 0.f);
                long off = (long)row * ldc + col;
                if (OUTF32) {
                    Cf[off] = v;
                } else {
                    unsigned short h = bf16_rne(v);
                    Ch[off] = h;
                    Cl[off] = bf16_rne(v - bf16_f(h));
                }
            }
        }
}

// ---------------------------------------------------------------------------
// Prep: A_t[i][k] = V[i][k] * sqrt(s_t[k]) -> bf16 hi/lo.
// ---------------------------------------------------------------------------
__global__ __launch_bounds__(256)
void prep_filter_A(const float* __restrict__ V, const float* __restrict__ sig, int t,
                   unsigned short* __restrict__ Ah, unsigned short* __restrict__ Al)
{
    long idx = ((long)blockIdx.x * 256 + threadIdx.x) * 4;
    int k = (int)(idx & (NN - 1));
    float4 v = *(const float4*)(V + idx);
    float a[4];
    a[0] = v.x * sqrtf(sig[(k + 0) * 4 + t]);
    a[1] = v.y * sqrtf(sig[(k + 1) * 4 + t]);
    a[2] = v.z * sqrtf(sig[(k + 2) * 4 + t]);
    a[3] = v.w * sqrtf(sig[(k + 3) * 4 + t]);
    ushort4 hi, lo;
    unsigned short h;
    h = bf16_rne(a[0]); hi.x = h; lo.x = bf16_rne(a[0] - bf16_f(h));
    h = bf16_rne(a[1]); hi.y = h; lo.y = bf16_rne(a[1] - bf16_f(h));
    h = bf16_rne(a[2]); hi.z = h; lo.z = bf16_rne(a[2] - bf16_f(h));
    h = bf16_rne(a[3]); hi.w = h; lo.w = bf16_rne(a[3] - bf16_f(h));
    *(ushort4*)(Ah + idx) = hi;
    *(ushort4*)(Al + idx) = lo;
}

// Elementwise fp32 -> bf16 hi/lo split (for x).
__global__ __launch_bounds__(256)
void split_kernel(const float* __restrict__ src,
                  unsigned short* __restrict__ oh, unsigned short* __restrict__ ol)
{
    long idx = ((long)blockIdx.x * 256 + threadIdx.x) * 4;
    float4 v = *(const float4*)(src + idx);
    float a[4] = {v.x, v.y, v.z, v.w};
    ushort4 hi, lo;
    unsigned short h;
    h = bf16_rne(a[0]); hi.x = h; lo.x = bf16_rne(a[0] - bf16_f(h));
    h = bf16_rne(a[1]); hi.y = h; lo.y = bf16_rne(a[1] - bf16_f(h));
    h = bf16_rne(a[2]); hi.z = h; lo.z = bf16_rne(a[2] - bf16_f(h));
    h = bf16_rne(a[3]); hi.w = h; lo.w = bf16_rne(a[3] - bf16_f(h));
    *(ushort4*)(oh + idx) = hi;
    *(ushort4*)(ol + idx) = lo;
}

// Transposed split: out[z][n][k] = (n < n_valid) ? src[z][k*src_ld + n] : 0
__global__ __launch_bounds__(256)
void transpose_split(const float* __restrict__ src, int src_ld, int n_rows, int n_valid,
                     int kcols, unsigned short* __restrict__ oh, unsigned short* __restrict__ ol,
                     long sbs, long sbd)
{
    long idx = (long)blockIdx.x * 256 + threadIdx.x;
    if (idx >= (long)n_rows * kcols) return;
    int n = (int)(idx / kcols), k = (int)(idx % kcols);
    float v = (n < n_valid) ? src[(long)blockIdx.y * sbs + (long)k * src_ld + n] : 0.f;
    unsigned short h = bf16_rne(v);
    long o = (long)blockIdx.y * sbd + idx;
    oh[o] = h;
    ol[o] = bf16_rne(v - bf16_f(h));
}

__global__ __launch_bounds__(256)
void zero_kernel(float* __restrict__ p)
{
    p[blockIdx.x * 256 + threadIdx.x] = 0.f;
}

__global__ __launch_bounds__(256)
void inv_kernel(const float* __restrict__ ss, float* __restrict__ inv)
{
    int i = blockIdx.x * 256 + threadIdx.x;
    inv[i] = 1.f / fmaxf(sqrtf(ss[i]), 1e-12f);
}

__global__ __launch_bounds__(256)
void prep_bg(const float* __restrict__ bg, float* __restrict__ bgp)
{
    int i = blockIdx.x * 256 + threadIdx.x;   // [4][256]
    int t = i >> 8, n = i & 255;
    bgp[i] = (n < 192) ? bg[t * 192 + n] : 0.f;
}

// gmask: in place  G = resplit( thresh( (hi+lo) * inv_row ) )
__global__ __launch_bounds__(256)
void gmask_kernel(unsigned short* __restrict__ Fh, unsigned short* __restrict__ Fl,
                  const float* __restrict__ inv)
{
    const int N = NN;
    int row = blockIdx.x, t = blockIdx.y;
    float iv = inv[t * N + row];
    long base = ((long)t * N + row) * N + threadIdx.x * 8;
    uint4 hv = *(const uint4*)(Fh + base);
    uint4 lv = *(const uint4*)(Fl + base);
    unsigned int ho[4], lo[4];
    const unsigned int* hp = (const unsigned int*)&hv;
    const unsigned int* lp = (const unsigned int*)&lv;
    #pragma unroll
    for (int d = 0; d < 4; ++d) {
        unsigned int hw = hp[d], lw = lp[d], hr = 0, lr = 0;
        #pragma unroll
        for (int e = 0; e < 2; ++e) {
            unsigned short hu = (unsigned short)(hw >> (16 * e));
            unsigned short lu = (unsigned short)(lw >> (16 * e));
            float f = bf16_f(hu) + bf16_f(lu);
            float g = f * iv;
            g = (fabsf(g) > 1e-4f) ? g : 0.f;
            unsigned short nh = bf16_rne(g);
            unsigned short nl = bf16_rne(g - bf16_f(nh));
            hr |= (unsigned int)nh << (16 * e);
            lr |= (unsigned int)nl << (16 * e);
        }
        ho[d] = hr; lo[d] = lr;
    }
    *(uint4*)(Fh + base) = *(uint4*)ho;
    *(uint4*)(Fl + base) = *(uint4*)lo;
}

// ---------------------------------------------------------------------------
extern "C" void kernel_launch(void* const* d_in, const int* in_sizes, int n_in,
                              void* d_out, int out_size, void* d_ws, size_t ws_size,
                              hipStream_t stream)
{
    const float* x   = (const float*)d_in[0];  // [2048][768]
    const float* evc = (const float*)d_in[1];  // [2048][2048]
    const float* sig = (const float*)d_in[2];  // [2048][4]
    const float* Wg  = (const float*)d_in[3];  // [4][768][192]
    const float* bg  = (const float*)d_in[4];  // [4][192]
    const float* Wf  = (const float*)d_in[5];  // [768][768]
    const float* bf  = (const float*)d_in[6];  // [768]
    float* out = (float*)d_out;                // [2048][768]

    char* w = (char*)d_ws;
    const long NPW = (long)NN * NN;            // elems per t-plane
    unsigned short* Fh = (unsigned short*)w;                    // [4][N][N] bf16
    unsigned short* Fl = Fh + 4 * NPW;
    char* R = w + 67108864L;
    // filter phase
    unsigned short* Ah = (unsigned short*)R;                    // [N][N]
    unsigned short* Al = Ah + NPW;
    // st1 phase (overlays R after filter)
    unsigned short* xh   = (unsigned short*)R;                  // [2048][768]
    unsigned short* xl   = xh + (long)NN * 768;
    unsigned short* WgTh = (unsigned short*)(R + 6291456L);     // [4][256][768]
    unsigned short* WgTl = WgTh + 4L * 256 * 768;
    unsigned short* PTh  = (unsigned short*)(R + 9437184L);     // [4][192][2048]
    unsigned short* PTl  = PTh + 4L * 192 * NN;
    // st4/5 phase
    unsigned short* HTh  = (unsigned short*)R;                  // [4][192][2048]
    unsigned short* HTl  = HTh + 4L * 192 * NN;
    unsigned short* combh = (unsigned short*)(R + 9437184L);    // [2048][768]
    unsigned short* combl = combh + (long)NN * 768;
    // st6 phase (overlays dead G region)
    unsigned short* WfTh = (unsigned short*)w;                  // [768][768]
    unsigned short* WfTl = WfTh + 768L * 768;
    // tail
    float* rowss = (float*)(w + 83886080L);                     // [4][2048]
    float* invv  = rowss + 4 * NN;                              // [4][2048]
    float* bgp   = invv + 4 * NN;                               // [4][256]

    zero_kernel<<<32, 256, 0, stream>>>(rowss);

    // filter: F_t = NT(A_t, A_t) with fused row-sumsq
    for (int t = 0; t < 4; ++t) {
        prep_filter_A<<<4096, 256, 0, stream>>>(evc, sig, t, Ah, Al);
        nt_gemm<0, false, false, true><<<dim3(16, 16, 1), 256, 0, stream>>>(
            Ah, Al, Ah, Al, Fh + t * NPW, Fl + t * NPW, nullptr,
            nullptr, rowss + t * NN,
            NN, NN, NN, NN, NN, NN, 0L, 0L, 0L, 0);
    }

    inv_kernel<<<32, 256, 0, stream>>>(rowss, invv);
    gmask_kernel<<<dim3(NN, 4), 256, 0, stream>>>(Fh, Fl, invv);

    // preps for st1
    split_kernel<<<1536, 256, 0, stream>>>(x, xh, xl);
    transpose_split<<<dim3(768, 4), 256, 0, stream>>>(
        Wg, 192, 256, 192, 768, WgTh, WgTl, 768L * 192, 256L * 768);
    prep_bg<<<4, 256, 0, stream>>>(bg, bgp);

    // st1: PT[t] = NT(WgT_pad[t], x)   [256->192 x 2048], K=768
    nt_gemm<0, false, false, false><<<dim3(16, 2, 4), 256, 0, stream>>>(
        WgTh, WgTl, xh, xl, PTh, PTl, nullptr, nullptr, nullptr,
        768, 256, NN, 192, NN, NN, 256L * 768, 0L, 192L * NN, 0);

    // st4: HT[t] = relu(NT(PT[t], G[t]) + bg[t])   [192 x 2048], K=2048
    nt_gemm<1, true, false, false><<<dim3(16, 2, 4), 256, 0, stream>>>(
        PTh, PTl, Fh, Fl, HTh, HTl, nullptr, bgp, nullptr,
        NN, 192, NN, 192, NN, NN, 192L * NN, NPW, 192L * NN, 256);

    // st5: comb[:, t*192:] = NT(G[t], HT[t])   [2048 x 192], K=2048
    nt_gemm<0, false, false, false><<<dim3(2, 16, 4), 256, 0, stream>>>(
        Fh, Fl, HTh, HTl, combh, combl, nullptr, nullptr, nullptr,
        NN, NN, 192, NN, 192, 768, NPW, 192L * NN, 192L, 0);

    // st6 prep + out = relu(NT(comb, WfT) + bf)   [2048 x 768], K=768
    transpose_split<<<dim3(2304, 1), 256, 0, stream>>>(
        Wf, 768, 768, 768, 768, WfTh, WfTl, 0L, 0L);
    nt_gemm<2, true, true, false><<<dim3(6, 16, 1), 256, 0, stream>>>(
        combh, combl, WfTh, WfTl, nullptr, nullptr, out, bf, nullptr,
        768, NN, 768, NN, 768, 768, 0L, 0L, 0L, 0);
}

// Round 4
// 549.276 us; speedup vs baseline: 1.9439x; 1.1324x over previous
//
#include <hip/hip_runtime.h>

// WaveGC wavelet conv. Round 4: re-tile NT-GEMM 128x128 -> 128x64.
// R3 post-mortem: filter grid was 256 blocks = 1 block/CU -> no inter-block
// overlap, MfmaUtil 22%. 128x64 tile doubles/quadruples grid sizes and cuts
// LDS to 48 KB (3 blocks/CU resident).
//
// NT-GEMM: C[i][j] = sum_k A[i][k]*B[j][k], A [M][K], B [N][K] row-major.
//  filter: F_t = NT(A_t, A_t) + fused row-sumsq            (A_t = V*sqrt(s_t))
//  gmask : G_t = resplit(thresh(F_t * inv_row))  in place
//  st1   : PT  = NT(WgT_pad, x)            [192(n) x 2048(m)]
//  st4   : HT  = relu(NT(PT, G) + bg)      [192(n) x 2048(m)]
//  st5   : comb= NT(G, HT)                 [2048(m) x 192(n)] -> cols t*192..
//  st6   : out = relu(NT(comb, WfT) + bf)  [2048 x 768] fp32
//
// ws overlay identical to R3 (peak 84.0 MB <= proven 86.0 MB).

#define NN 2048

typedef short bf16x8 __attribute__((ext_vector_type(8)));
typedef float f32x4  __attribute__((ext_vector_type(4)));

__device__ inline unsigned short bf16_rne(float f) {
    unsigned int u = __float_as_uint(f);
    u += 0x7fffu + ((u >> 16) & 1u);
    return (unsigned short)(u >> 16);
}
__device__ inline float bf16_f(unsigned short h) {
    return __uint_as_float((unsigned)h << 16);
}

// ---------------------------------------------------------------------------
// Split-bf16 NT MFMA GEMM. 128(m) x 64(n) block, BK=64, 256 threads:
// 4 waves, each 32(m) x 64(n) = 2x4 frags of 16x16. LDS 48 KB -> 3 blocks/CU.
// XOR-swizzled LDS; 3-mfma split (hh, hl, lh) per fragment pair.
// BIASM: 0 none, 1 per-row (bias[i]), 2 per-col (bias[j]).
// ---------------------------------------------------------------------------
template<int BIASM, bool RELU, bool OUTF32, bool SUMSQ>
__global__ __launch_bounds__(256, 3)
void nt_gemm(const unsigned short* __restrict__ Ah, const unsigned short* __restrict__ Al,
             const unsigned short* __restrict__ Bh, const unsigned short* __restrict__ Bl,
             unsigned short* __restrict__ Ch, unsigned short* __restrict__ Cl,
             float* __restrict__ Cf,
             const float* __restrict__ bias, float* __restrict__ sumsq,
             int K, int a_rows, int b_rows, int i_valid, int j_valid, int ldc,
             long sA, long sB, long sC, int sBias)
{
    __shared__ unsigned short sAh[128 * 64];
    __shared__ unsigned short sAl[128 * 64];
    __shared__ unsigned short sBh[64 * 64];
    __shared__ unsigned short sBl[64 * 64];

    int z = blockIdx.z;
    Ah += z * sA; Al += z * sA;
    Bh += z * sB; Bl += z * sB;
    if (OUTF32) Cf += z * sC; else { Ch += z * sC; Cl += z * sC; }
    if (BIASM)  bias += (long)z * sBias;

    int i0 = blockIdx.y * 128, j0 = blockIdx.x * 64;
    int tid = threadIdx.x;
    int lane = tid & 63, w = tid >> 6;
    int wr = w * 32;                      // wave covers rows wr..wr+31, all 64 cols
    int q = lane >> 4, r15 = lane & 15;

    f32x4 acc[2][4];
    #pragma unroll
    for (int i = 0; i < 2; ++i)
        #pragma unroll
        for (int j = 0; j < 4; ++j)
            acc[i][j] = (f32x4){0.f, 0.f, 0.f, 0.f};

    for (int k0 = 0; k0 < K; k0 += 64) {
        // A tile: 128 rows x 64 k  -> 4 chunks/thread
        #pragma unroll
        for (int p = 0; p < 4; ++p) {
            int c = p * 256 + tid;
            int row = c >> 3, g = c & 7;
            int dst = row * 64 + ((g ^ (row & 7)) * 8);
            int ra = min(i0 + row, a_rows - 1);
            long offA = (long)ra * K + k0 + g * 8;
            *(uint4*)&sAh[dst] = *(const uint4*)(Ah + offA);
            *(uint4*)&sAl[dst] = *(const uint4*)(Al + offA);
        }
        // B tile: 64 rows x 64 k -> 2 chunks/thread
        #pragma unroll
        for (int p = 0; p < 2; ++p) {
            int c = p * 256 + tid;
            int row = c >> 3, g = c & 7;
            int dst = row * 64 + ((g ^ (row & 7)) * 8);
            int rb = min(j0 + row, b_rows - 1);
            long offB = (long)rb * K + k0 + g * 8;
            *(uint4*)&sBh[dst] = *(const uint4*)(Bh + offB);
            *(uint4*)&sBl[dst] = *(const uint4*)(Bl + offB);
        }
        __syncthreads();

        #pragma unroll
        for (int s = 0; s < 2; ++s) {
            int g = s * 4 + q;
            bf16x8 fAh[2], fAl[2], fBh[4], fBl[4];
            #pragma unroll
            for (int f = 0; f < 2; ++f) {
                int ra = wr + f * 16 + r15;
                int aa = ra * 64 + ((g ^ (ra & 7)) * 8);
                fAh[f] = *(const bf16x8*)&sAh[aa];
                fAl[f] = *(const bf16x8*)&sAl[aa];
            }
            #pragma unroll
            for (int f = 0; f < 4; ++f) {
                int rb = f * 16 + r15;
                int ab = rb * 64 + ((g ^ (rb & 7)) * 8);
                fBh[f] = *(const bf16x8*)&sBh[ab];
                fBl[f] = *(const bf16x8*)&sBl[ab];
            }
            #pragma unroll
            for (int fi = 0; fi < 2; ++fi)
                #pragma unroll
                for (int fj = 0; fj < 4; ++fj) {
                    acc[fi][fj] = __builtin_amdgcn_mfma_f32_16x16x32_bf16(
                        fAh[fi], fBh[fj], acc[fi][fj], 0, 0, 0);
                    acc[fi][fj] = __builtin_amdgcn_mfma_f32_16x16x32_bf16(
                        fAh[fi], fBl[fj], acc[fi][fj], 0, 0, 0);
                    acc[fi][fj] = __builtin_amdgcn_mfma_f32_16x16x32_bf16(
                        fAl[fi], fBh[fj], acc[fi][fj], 0, 0, 0);
                }
        }
        __syncthreads();
    }

    if (SUMSQ) {
        #pragma unroll
        for (int fi = 0; fi < 2; ++fi)
            #pragma unroll
            for (int r = 0; r < 4; ++r) {
                float s = 0.f;
                #pragma unroll
                for (int fj = 0; fj < 4; ++fj) {
                    float v = acc[fi][fj][r];
                    s += v * v;
                }
                s += __shfl_xor(s, 1); s += __shfl_xor(s, 2);
                s += __shfl_xor(s, 4); s += __shfl_xor(s, 8);
                if (r15 == 0)
                    atomicAdd(&sumsq[i0 + wr + fi * 16 + q * 4 + r], s);
            }
    }

    #pragma unroll
    for (int fi = 0; fi < 2; ++fi)
        #pragma unroll
        for (int fj = 0; fj < 4; ++fj) {
            int col = j0 + fj * 16 + r15;
            if (col >= j_valid) continue;
            #pragma unroll
            for (int r = 0; r < 4; ++r) {
                int row = i0 + wr + fi * 16 + q * 4 + r;
                if (row >= i_valid) continue;
                float v = acc[fi][fj][r];
                if (BIASM == 1) v += bias[row];
                if (BIASM == 2) v += bias[col];
                if (RELU) v = fmaxf(v, 0.f);
                long off = (long)row * ldc + col;
                if (OUTF32) {
                    Cf[off] = v;
                } else {
                    unsigned short h = bf16_rne(v);
                    Ch[off] = h;
                    Cl[off] = bf16_rne(v - bf16_f(h));
                }
            }
        }
}

// ---------------------------------------------------------------------------
// Prep: A_t[i][k] = V[i][k] * sqrt(s_t[k]) -> bf16 hi/lo.
// ---------------------------------------------------------------------------
__global__ __launch_bounds__(256)
void prep_filter_A(const float* __restrict__ V, const float* __restrict__ sig, int t,
                   unsigned short* __restrict__ Ah, unsigned short* __restrict__ Al)
{
    long idx = ((long)blockIdx.x * 256 + threadIdx.x) * 4;
    int k = (int)(idx & (NN - 1));
    float4 v = *(const float4*)(V + idx);
    float a[4];
    a[0] = v.x * sqrtf(sig[(k + 0) * 4 + t]);
    a[1] = v.y * sqrtf(sig[(k + 1) * 4 + t]);
    a[2] = v.z * sqrtf(sig[(k + 2) * 4 + t]);
    a[3] = v.w * sqrtf(sig[(k + 3) * 4 + t]);
    ushort4 hi, lo;
    unsigned short h;
    h = bf16_rne(a[0]); hi.x = h; lo.x = bf16_rne(a[0] - bf16_f(h));
    h = bf16_rne(a[1]); hi.y = h; lo.y = bf16_rne(a[1] - bf16_f(h));
    h = bf16_rne(a[2]); hi.z = h; lo.z = bf16_rne(a[2] - bf16_f(h));
    h = bf16_rne(a[3]); hi.w = h; lo.w = bf16_rne(a[3] - bf16_f(h));
    *(ushort4*)(Ah + idx) = hi;
    *(ushort4*)(Al + idx) = lo;
}

// Elementwise fp32 -> bf16 hi/lo split (for x).
__global__ __launch_bounds__(256)
void split_kernel(const float* __restrict__ src,
                  unsigned short* __restrict__ oh, unsigned short* __restrict__ ol)
{
    long idx = ((long)blockIdx.x * 256 + threadIdx.x) * 4;
    float4 v = *(const float4*)(src + idx);
    float a[4] = {v.x, v.y, v.z, v.w};
    ushort4 hi, lo;
    unsigned short h;
    h = bf16_rne(a[0]); hi.x = h; lo.x = bf16_rne(a[0] - bf16_f(h));
    h = bf16_rne(a[1]); hi.y = h; lo.y = bf16_rne(a[1] - bf16_f(h));
    h = bf16_rne(a[2]); hi.z = h; lo.z = bf16_rne(a[2] - bf16_f(h));
    h = bf16_rne(a[3]); hi.w = h; lo.w = bf16_rne(a[3] - bf16_f(h));
    *(ushort4*)(oh + idx) = hi;
    *(ushort4*)(ol + idx) = lo;
}

// Transposed split: out[z][n][k] = (n < n_valid) ? src[z][k*src_ld + n] : 0
__global__ __launch_bounds__(256)
void transpose_split(const float* __restrict__ src, int src_ld, int n_rows, int n_valid,
                     int kcols, unsigned short* __restrict__ oh, unsigned short* __restrict__ ol,
                     long sbs, long sbd)
{
    long idx = (long)blockIdx.x * 256 + threadIdx.x;
    if (idx >= (long)n_rows * kcols) return;
    int n = (int)(idx / kcols), k = (int)(idx % kcols);
    float v = (n < n_valid) ? src[(long)blockIdx.y * sbs + (long)k * src_ld + n] : 0.f;
    unsigned short h = bf16_rne(v);
    long o = (long)blockIdx.y * sbd + idx;
    oh[o] = h;
    ol[o] = bf16_rne(v - bf16_f(h));
}

__global__ __launch_bounds__(256)
void zero_kernel(float* __restrict__ p)
{
    p[blockIdx.x * 256 + threadIdx.x] = 0.f;
}

__global__ __launch_bounds__(256)
void inv_kernel(const float* __restrict__ ss, float* __restrict__ inv)
{
    int i = blockIdx.x * 256 + threadIdx.x;
    inv[i] = 1.f / fmaxf(sqrtf(ss[i]), 1e-12f);
}

__global__ __launch_bounds__(256)
void prep_bg(const float* __restrict__ bg, float* __restrict__ bgp)
{
    int i = blockIdx.x * 256 + threadIdx.x;   // [4][256]
    int t = i >> 8, n = i & 255;
    bgp[i] = (n < 192) ? bg[t * 192 + n] : 0.f;
}

// gmask: in place  G = resplit( thresh( (hi+lo) * inv_row ) )
__global__ __launch_bounds__(256)
void gmask_kernel(unsigned short* __restrict__ Fh, unsigned short* __restrict__ Fl,
                  const float* __restrict__ inv)
{
    const int N = NN;
    int row = blockIdx.x, t = blockIdx.y;
    float iv = inv[t * N + row];
    long base = ((long)t * N + row) * N + threadIdx.x * 8;
    uint4 hv = *(const uint4*)(Fh + base);
    uint4 lv = *(const uint4*)(Fl + base);
    unsigned int ho[4], lo[4];
    const unsigned int* hp = (const unsigned int*)&hv;
    const unsigned int* lp = (const unsigned int*)&lv;
    #pragma unroll
    for (int d = 0; d < 4; ++d) {
        unsigned int hw = hp[d], lw = lp[d], hr = 0, lr = 0;
        #pragma unroll
        for (int e = 0; e < 2; ++e) {
            unsigned short hu = (unsigned short)(hw >> (16 * e));
            unsigned short lu = (unsigned short)(lw >> (16 * e));
            float f = bf16_f(hu) + bf16_f(lu);
            float g = f * iv;
            g = (fabsf(g) > 1e-4f) ? g : 0.f;
            unsigned short nh = bf16_rne(g);
            unsigned short nl = bf16_rne(g - bf16_f(nh));
            hr |= (unsigned int)nh << (16 * e);
            lr |= (unsigned int)nl << (16 * e);
        }
        ho[d] = hr; lo[d] = lr;
    }
    *(uint4*)(Fh + base) = *(uint4*)ho;
    *(uint4*)(Fl + base) = *(uint4*)lo;
}

// ---------------------------------------------------------------------------
extern "C" void kernel_launch(void* const* d_in, const int* in_sizes, int n_in,
                              void* d_out, int out_size, void* d_ws, size_t ws_size,
                              hipStream_t stream)
{
    const float* x   = (const float*)d_in[0];  // [2048][768]
    const float* evc = (const float*)d_in[1];  // [2048][2048]
    const float* sig = (const float*)d_in[2];  // [2048][4]
    const float* Wg  = (const float*)d_in[3];  // [4][768][192]
    const float* bg  = (const float*)d_in[4];  // [4][192]
    const float* Wf  = (const float*)d_in[5];  // [768][768]
    const float* bf  = (const float*)d_in[6];  // [768]
    float* out = (float*)d_out;                // [2048][768]

    char* w = (char*)d_ws;
    const long NPW = (long)NN * NN;            // elems per t-plane
    unsigned short* Fh = (unsigned short*)w;                    // [4][N][N] bf16
    unsigned short* Fl = Fh + 4 * NPW;
    char* R = w + 67108864L;
    // filter phase
    unsigned short* Ah = (unsigned short*)R;                    // [N][N]
    unsigned short* Al = Ah + NPW;
    // st1 phase (overlays R after filter)
    unsigned short* xh   = (unsigned short*)R;                  // [2048][768]
    unsigned short* xl   = xh + (long)NN * 768;
    unsigned short* WgTh = (unsigned short*)(R + 6291456L);     // [4][256][768]
    unsigned short* WgTl = WgTh + 4L * 256 * 768;
    unsigned short* PTh  = (unsigned short*)(R + 9437184L);     // [4][192][2048]
    unsigned short* PTl  = PTh + 4L * 192 * NN;
    // st4/5 phase
    unsigned short* HTh  = (unsigned short*)R;                  // [4][192][2048]
    unsigned short* HTl  = HTh + 4L * 192 * NN;
    unsigned short* combh = (unsigned short*)(R + 9437184L);    // [2048][768]
    unsigned short* combl = combh + (long)NN * 768;
    // st6 phase (overlays dead G region)
    unsigned short* WfTh = (unsigned short*)w;                  // [768][768]
    unsigned short* WfTl = WfTh + 768L * 768;
    // tail
    float* rowss = (float*)(w + 83886080L);                     // [4][2048]
    float* invv  = rowss + 4 * NN;                              // [4][2048]
    float* bgp   = invv + 4 * NN;                               // [4][256]

    zero_kernel<<<32, 256, 0, stream>>>(rowss);

    // filter: F_t = NT(A_t, A_t) with fused row-sumsq.  grid 32x16 = 512 blocks.
    for (int t = 0; t < 4; ++t) {
        prep_filter_A<<<4096, 256, 0, stream>>>(evc, sig, t, Ah, Al);
        nt_gemm<0, false, false, true><<<dim3(32, 16, 1), 256, 0, stream>>>(
            Ah, Al, Ah, Al, Fh + t * NPW, Fl + t * NPW, nullptr,
            nullptr, rowss + t * NN,
            NN, NN, NN, NN, NN, NN, 0L, 0L, 0L, 0);
    }

    inv_kernel<<<32, 256, 0, stream>>>(rowss, invv);
    gmask_kernel<<<dim3(NN, 4), 256, 0, stream>>>(Fh, Fl, invv);

    // preps for st1
    split_kernel<<<1536, 256, 0, stream>>>(x, xh, xl);
    transpose_split<<<dim3(768, 4), 256, 0, stream>>>(
        Wg, 192, 256, 192, 768, WgTh, WgTl, 768L * 192, 256L * 768);
    prep_bg<<<4, 256, 0, stream>>>(bg, bgp);

    // st1: PT[t] = NT(WgT_pad[t], x)   [256->192 x 2048], K=768. grid 32x2x4=256
    nt_gemm<0, false, false, false><<<dim3(32, 2, 4), 256, 0, stream>>>(
        WgTh, WgTl, xh, xl, PTh, PTl, nullptr, nullptr, nullptr,
        768, 256, NN, 192, NN, NN, 256L * 768, 0L, 192L * NN, 0);

    // st4: HT[t] = relu(NT(PT[t], G[t]) + bg[t])   [192 x 2048], K=2048. 256 blocks
    nt_gemm<1, true, false, false><<<dim3(32, 2, 4), 256, 0, stream>>>(
        PTh, PTl, Fh, Fl, HTh, HTl, nullptr, bgp, nullptr,
        NN, 192, NN, 192, NN, NN, 192L * NN, NPW, 192L * NN, 256);

    // st5: comb[:, t*192:] = NT(G[t], HT[t])   [2048 x 192], K=2048. 192 blocks
    nt_gemm<0, false, false, false><<<dim3(3, 16, 4), 256, 0, stream>>>(
        Fh, Fl, HTh, HTl, combh, combl, nullptr, nullptr, nullptr,
        NN, NN, 192, NN, 192, 768, NPW, 192L * NN, 192L, 0);

    // st6 prep + out = relu(NT(comb, WfT) + bf)   [2048 x 768], K=768. 192 blocks
    transpose_split<<<dim3(2304, 1), 256, 0, stream>>>(
        Wf, 768, 768, 768, 768, WfTh, WfTl, 0L, 0L);
    nt_gemm<2, true, true, false><<<dim3(12, 16, 1), 256, 0, stream>>>(
        combh, combl, WfTh, WfTl, nullptr, nullptr, out, bf, nullptr,
        768, NN, 768, NN, 768, 768, 0L, 0L, 0L, 0);
}

// Round 5
// 509.405 us; speedup vs baseline: 2.0960x; 1.0783x over previous
//
#include <hip/hip_runtime.h>

// WaveGC wavelet conv. Round 5: global_load_lds (width-16 DMA) staging.
// R4 post-mortem: LDS pipe was critical (reads + staging writes ~1440 cyc/k-step
// vs 922 MFMA); manual staging also burned VALU + VGPRs. DMA staging removes the
// ds_writes and the VGPR round-trip; XOR swizzle moved to the global address side
// (read-side fragment addressing unchanged, proven conflict-free).
//
// NT-GEMM: C[i][j] = sum_k A[i][k]*B[j][k], A [M][K], B [N][K] row-major.
//  filter: F_t = NT(A_t, A_t) + fused row-sumsq            (A_t = V*sqrt(s_t))
//  gmask : G_t = resplit(thresh(F_t * inv_row))  in place  (inv fused in)
//  st1   : PT  = NT(WgT_pad, x)            [192(n) x 2048(m)]
//  st4   : HT  = relu(NT(PT, G) + bg)      [192(n) x 2048(m)]
//  st5   : comb= NT(G, HT)                 [2048(m) x 192(n)] -> cols t*192..
//  st6   : out = relu(NT(comb, WfT) + bf)  [2048 x 768] fp32
//
// ws overlay (peak 84.0 MB <= proven 86.0 MB), same as R3/R4.

#define NN 2048

typedef short bf16x8 __attribute__((ext_vector_type(8)));
typedef float f32x4  __attribute__((ext_vector_type(4)));

__device__ inline unsigned short bf16_rne(float f) {
    unsigned int u = __float_as_uint(f);
    u += 0x7fffu + ((u >> 16) & 1u);
    return (unsigned short)(u >> 16);
}
__device__ inline float bf16_f(unsigned short h) {
    return __uint_as_float((unsigned)h << 16);
}

// Async global->LDS DMA, 16B per lane. LDS dest = wave-uniform base + lane*16.
// AS3 pointers are 32-bit; truncating the flat LDS address yields the LDS offset.
__device__ inline void load_lds16(const void* g, void* l) {
    __builtin_amdgcn_global_load_lds(
        (const __attribute__((address_space(1))) unsigned int*)(unsigned long)g,
        (__attribute__((address_space(3))) unsigned int*)(unsigned long)l,
        16, 0, 0);
}

// ---------------------------------------------------------------------------
// Split-bf16 NT MFMA GEMM. 128(m) x 64(n) block, BK=64, 256 threads:
// 4 waves, each 32(m) x 64(n) = 2x4 frags of 16x16. LDS 48 KB -> 3 blocks/CU.
// Staging via global_load_lds: lane reads global chunk g^(row&7), DMA writes
// LDS linearly; so LDS[row*64 + p*8] holds global chunk p^(row&7) — identical
// swizzle as R4, fragment read addressing unchanged (0 bank conflicts).
// 3-mfma split (hh, hl, lh) per fragment pair.
// BIASM: 0 none, 1 per-row (bias[i]), 2 per-col (bias[j]).
// ---------------------------------------------------------------------------
template<int BIASM, bool RELU, bool OUTF32, bool SUMSQ>
__global__ __launch_bounds__(256, 3)
void nt_gemm(const unsigned short* __restrict__ Ah, const unsigned short* __restrict__ Al,
             const unsigned short* __restrict__ Bh, const unsigned short* __restrict__ Bl,
             unsigned short* __restrict__ Ch, unsigned short* __restrict__ Cl,
             float* __restrict__ Cf,
             const float* __restrict__ bias, float* __restrict__ sumsq,
             int K, int a_rows, int b_rows, int i_valid, int j_valid, int ldc,
             long sA, long sB, long sC, int sBias)
{
    __shared__ unsigned short sAh[128 * 64];
    __shared__ unsigned short sAl[128 * 64];
    __shared__ unsigned short sBh[64 * 64];
    __shared__ unsigned short sBl[64 * 64];

    int z = blockIdx.z;
    Ah += z * sA; Al += z * sA;
    Bh += z * sB; Bl += z * sB;
    if (OUTF32) Cf += z * sC; else { Ch += z * sC; Cl += z * sC; }
    if (BIASM)  bias += (long)z * sBias;

    int i0 = blockIdx.y * 128, j0 = blockIdx.x * 64;
    int tid = threadIdx.x;
    int lane = tid & 63, w = tid >> 6;
    int wbase = w * 64;                   // wave-uniform chunk base
    int wr = w * 32;                      // wave covers rows wr..wr+31, all 64 cols
    int q = lane >> 4, r15 = lane & 15;

    // per-lane global row/chunk decode for DMA staging
    f32x4 acc[2][4];
    #pragma unroll
    for (int i = 0; i < 2; ++i)
        #pragma unroll
        for (int j = 0; j < 4; ++j)
            acc[i][j] = (f32x4){0.f, 0.f, 0.f, 0.f};

    for (int k0 = 0; k0 < K; k0 += 64) {
        // A tile: 128 rows x 64 k -> 4 wave-chunks of 1 KB per array
        #pragma unroll
        for (int p = 0; p < 4; ++p) {
            int c = p * 256 + wbase + lane;
            int row = c >> 3;
            int gsw = (c & 7) ^ (row & 7);
            int ra = min(i0 + row, a_rows - 1);
            long off = (long)ra * K + k0 + gsw * 8;
            int ldst = (p * 256 + wbase) * 8;
            load_lds16(Ah + off, &sAh[ldst]);
            load_lds16(Al + off, &sAl[ldst]);
        }
        // B tile: 64 rows x 64 k -> 2 wave-chunks per array
        #pragma unroll
        for (int p = 0; p < 2; ++p) {
            int c = p * 256 + wbase + lane;
            int row = c >> 3;
            int gsw = (c & 7) ^ (row & 7);
            int rb = min(j0 + row, b_rows - 1);
            long off = (long)rb * K + k0 + gsw * 8;
            int ldst = (p * 256 + wbase) * 8;
            load_lds16(Bh + off, &sBh[ldst]);
            load_lds16(Bl + off, &sBl[ldst]);
        }
        __syncthreads();   // drains vmcnt (DMA) before any fragment read

        #pragma unroll
        for (int s = 0; s < 2; ++s) {
            int g = s * 4 + q;
            bf16x8 fAh[2], fAl[2], fBh[4], fBl[4];
            #pragma unroll
            for (int f = 0; f < 2; ++f) {
                int ra = wr + f * 16 + r15;
                int aa = ra * 64 + ((g ^ (ra & 7)) * 8);
                fAh[f] = *(const bf16x8*)&sAh[aa];
                fAl[f] = *(const bf16x8*)&sAl[aa];
            }
            #pragma unroll
            for (int f = 0; f < 4; ++f) {
                int rb = f * 16 + r15;
                int ab = rb * 64 + ((g ^ (rb & 7)) * 8);
                fBh[f] = *(const bf16x8*)&sBh[ab];
                fBl[f] = *(const bf16x8*)&sBl[ab];
            }
            #pragma unroll
            for (int fi = 0; fi < 2; ++fi)
                #pragma unroll
                for (int fj = 0; fj < 4; ++fj) {
                    acc[fi][fj] = __builtin_amdgcn_mfma_f32_16x16x32_bf16(
                        fAh[fi], fBh[fj], acc[fi][fj], 0, 0, 0);
                    acc[fi][fj] = __builtin_amdgcn_mfma_f32_16x16x32_bf16(
                        fAh[fi], fBl[fj], acc[fi][fj], 0, 0, 0);
                    acc[fi][fj] = __builtin_amdgcn_mfma_f32_16x16x32_bf16(
                        fAl[fi], fBh[fj], acc[fi][fj], 0, 0, 0);
                }
        }
        __syncthreads();
    }

    if (SUMSQ) {
        #pragma unroll
        for (int fi = 0; fi < 2; ++fi)
            #pragma unroll
            for (int r = 0; r < 4; ++r) {
                float s = 0.f;
                #pragma unroll
                for (int fj = 0; fj < 4; ++fj) {
                    float v = acc[fi][fj][r];
                    s += v * v;
                }
                s += __shfl_xor(s, 1); s += __shfl_xor(s, 2);
                s += __shfl_xor(s, 4); s += __shfl_xor(s, 8);
                if (r15 == 0)
                    atomicAdd(&sumsq[i0 + wr + fi * 16 + q * 4 + r], s);
            }
    }

    #pragma unroll
    for (int fi = 0; fi < 2; ++fi)
        #pragma unroll
        for (int fj = 0; fj < 4; ++fj) {
            int col = j0 + fj * 16 + r15;
            if (col >= j_valid) continue;
            #pragma unroll
            for (int r = 0; r < 4; ++r) {
                int row = i0 + wr + fi * 16 + q * 4 + r;
                if (row >= i_valid) continue;
                float v = acc[fi][fj][r];
                if (BIASM == 1) v += bias[row];
                if (BIASM == 2) v += bias[col];
                if (RELU) v = fmaxf(v, 0.f);
                long off = (long)row * ldc + col;
                if (OUTF32) {
                    Cf[off] = v;
                } else {
                    unsigned short h = bf16_rne(v);
                    Ch[off] = h;
                    Cl[off] = bf16_rne(v - bf16_f(h));
                }
            }
        }
}

// ---------------------------------------------------------------------------
// Prep: A_t[i][k] = V[i][k] * sqrt(s_t[k]) -> bf16 hi/lo.
// Also zeroes the sumsq accumulator when zs != nullptr (t=0 launch only).
// ---------------------------------------------------------------------------
__global__ __launch_bounds__(256)
void prep_filter_A(const float* __restrict__ V, const float* __restrict__ sig, int t,
                   unsigned short* __restrict__ Ah, unsigned short* __restrict__ Al,
                   float* __restrict__ zs)
{
    if (zs && blockIdx.x < 32)
        zs[blockIdx.x * 256 + threadIdx.x] = 0.f;   // 8192 floats = [4][2048]
    long idx = ((long)blockIdx.x * 256 + threadIdx.x) * 4;
    int k = (int)(idx & (NN - 1));
    float4 v = *(const float4*)(V + idx);
    float a[4];
    a[0] = v.x * sqrtf(sig[(k + 0) * 4 + t]);
    a[1] = v.y * sqrtf(sig[(k + 1) * 4 + t]);
    a[2] = v.z * sqrtf(sig[(k + 2) * 4 + t]);
    a[3] = v.w * sqrtf(sig[(k + 3) * 4 + t]);
    ushort4 hi, lo;
    unsigned short h;
    h = bf16_rne(a[0]); hi.x = h; lo.x = bf16_rne(a[0] - bf16_f(h));
    h = bf16_rne(a[1]); hi.y = h; lo.y = bf16_rne(a[1] - bf16_f(h));
    h = bf16_rne(a[2]); hi.z = h; lo.z = bf16_rne(a[2] - bf16_f(h));
    h = bf16_rne(a[3]); hi.w = h; lo.w = bf16_rne(a[3] - bf16_f(h));
    *(ushort4*)(Ah + idx) = hi;
    *(ushort4*)(Al + idx) = lo;
}

// Elementwise fp32 -> bf16 hi/lo split (x); block 0 also pads bg -> bgp [4][256].
__global__ __launch_bounds__(256)
void split_kernel(const float* __restrict__ src,
                  unsigned short* __restrict__ oh, unsigned short* __restrict__ ol,
                  const float* __restrict__ bg, float* __restrict__ bgp)
{
    if (blockIdx.x == 0 && bgp) {
        #pragma unroll
        for (int p = 0; p < 4; ++p) {
            int i = p * 256 + threadIdx.x;
            int t = i >> 8, n = i & 255;
            bgp[i] = (n < 192) ? bg[t * 192 + n] : 0.f;
        }
    }
    long idx = ((long)blockIdx.x * 256 + threadIdx.x) * 4;
    float4 v = *(const float4*)(src + idx);
    float a[4] = {v.x, v.y, v.z, v.w};
    ushort4 hi, lo;
    unsigned short h;
    h = bf16_rne(a[0]); hi.x = h; lo.x = bf16_rne(a[0] - bf16_f(h));
    h = bf16_rne(a[1]); hi.y = h; lo.y = bf16_rne(a[1] - bf16_f(h));
    h = bf16_rne(a[2]); hi.z = h; lo.z = bf16_rne(a[2] - bf16_f(h));
    h = bf16_rne(a[3]); hi.w = h; lo.w = bf16_rne(a[3] - bf16_f(h));
    *(ushort4*)(oh + idx) = hi;
    *(ushort4*)(ol + idx) = lo;
}

// Transposed split: out[z][n][k] = (n < n_valid) ? src[z][k*src_ld + n] : 0
__global__ __launch_bounds__(256)
void transpose_split(const float* __restrict__ src, int src_ld, int n_rows, int n_valid,
                     int kcols, unsigned short* __restrict__ oh, unsigned short* __restrict__ ol,
                     long sbs, long sbd)
{
    long idx = (long)blockIdx.x * 256 + threadIdx.x;
    if (idx >= (long)n_rows * kcols) return;
    int n = (int)(idx / kcols), k = (int)(idx % kcols);
    float v = (n < n_valid) ? src[(long)blockIdx.y * sbs + (long)k * src_ld + n] : 0.f;
    unsigned short h = bf16_rne(v);
    long o = (long)blockIdx.y * sbd + idx;
    oh[o] = h;
    ol[o] = bf16_rne(v - bf16_f(h));
}

// gmask: in place  G = resplit( thresh( (hi+lo) * 1/max(sqrt(ss),1e-12) ) )
__global__ __launch_bounds__(256)
void gmask_kernel(unsigned short* __restrict__ Fh, unsigned short* __restrict__ Fl,
                  const float* __restrict__ rowss)
{
    const int N = NN;
    int row = blockIdx.x, t = blockIdx.y;
    float iv = 1.f / fmaxf(sqrtf(rowss[t * N + row]), 1e-12f);
    long base = ((long)t * N + row) * N + threadIdx.x * 8;
    uint4 hv = *(const uint4*)(Fh + base);
    uint4 lv = *(const uint4*)(Fl + base);
    unsigned int ho[4], lo[4];
    const unsigned int* hp = (const unsigned int*)&hv;
    const unsigned int* lp = (const unsigned int*)&lv;
    #pragma unroll
    for (int d = 0; d < 4; ++d) {
        unsigned int hw = hp[d], lw = lp[d], hr = 0, lr = 0;
        #pragma unroll
        for (int e = 0; e < 2; ++e) {
            unsigned short hu = (unsigned short)(hw >> (16 * e));
            unsigned short lu = (unsigned short)(lw >> (16 * e));
            float f = bf16_f(hu) + bf16_f(lu);
            float g = f * iv;
            g = (fabsf(g) > 1e-4f) ? g : 0.f;
            unsigned short nh = bf16_rne(g);
            unsigned short nl = bf16_rne(g - bf16_f(nh));
            hr |= (unsigned int)nh << (16 * e);
            lr |= (unsigned int)nl << (16 * e);
        }
        ho[d] = hr; lo[d] = lr;
    }
    *(uint4*)(Fh + base) = *(uint4*)ho;
    *(uint4*)(Fl + base) = *(uint4*)lo;
}

// ---------------------------------------------------------------------------
extern "C" void kernel_launch(void* const* d_in, const int* in_sizes, int n_in,
                              void* d_out, int out_size, void* d_ws, size_t ws_size,
                              hipStream_t stream)
{
    const float* x   = (const float*)d_in[0];  // [2048][768]
    const float* evc = (const float*)d_in[1];  // [2048][2048]
    const float* sig = (const float*)d_in[2];  // [2048][4]
    const float* Wg  = (const float*)d_in[3];  // [4][768][192]
    const float* bg  = (const float*)d_in[4];  // [4][192]
    const float* Wf  = (const float*)d_in[5];  // [768][768]
    const float* bf  = (const float*)d_in[6];  // [768]
    float* out = (float*)d_out;                // [2048][768]

    char* w = (char*)d_ws;
    const long NPW = (long)NN * NN;            // elems per t-plane
    unsigned short* Fh = (unsigned short*)w;                    // [4][N][N] bf16
    unsigned short* Fl = Fh + 4 * NPW;
    char* R = w + 67108864L;
    // filter phase
    unsigned short* Ah = (unsigned short*)R;                    // [N][N]
    unsigned short* Al = Ah + NPW;
    // st1 phase (overlays R after filter)
    unsigned short* xh   = (unsigned short*)R;                  // [2048][768]
    unsigned short* xl   = xh + (long)NN * 768;
    unsigned short* WgTh = (unsigned short*)(R + 6291456L);     // [4][256][768]
    unsigned short* WgTl = WgTh + 4L * 256 * 768;
    unsigned short* PTh  = (unsigned short*)(R + 9437184L);     // [4][192][2048]
    unsigned short* PTl  = PTh + 4L * 192 * NN;
    // st4/5 phase
    unsigned short* HTh  = (unsigned short*)R;                  // [4][192][2048]
    unsigned short* HTl  = HTh + 4L * 192 * NN;
    unsigned short* combh = (unsigned short*)(R + 9437184L);    // [2048][768]
    unsigned short* combl = combh + (long)NN * 768;
    // st6 phase (overlays dead G region)
    unsigned short* WfTh = (unsigned short*)w;                  // [768][768]
    unsigned short* WfTl = WfTh + 768L * 768;
    // tail
    float* rowss = (float*)(w + 83886080L);                     // [4][2048]
    float* bgp   = rowss + 4 * NN;                              // [4][256]

    // filter: F_t = NT(A_t, A_t) with fused row-sumsq.  grid 32x16 = 512 blocks.
    for (int t = 0; t < 4; ++t) {
        prep_filter_A<<<4096, 256, 0, stream>>>(evc, sig, t, Ah, Al,
                                                t == 0 ? rowss : nullptr);
        nt_gemm<0, false, false, true><<<dim3(32, 16, 1), 256, 0, stream>>>(
            Ah, Al, Ah, Al, Fh + t * NPW, Fl + t * NPW, nullptr,
            nullptr, rowss + t * NN,
            NN, NN, NN, NN, NN, NN, 0L, 0L, 0L, 0);
    }

    gmask_kernel<<<dim3(NN, 4), 256, 0, stream>>>(Fh, Fl, rowss);

    // preps for st1 (R region is free now)
    split_kernel<<<1536, 256, 0, stream>>>(x, xh, xl, bg, bgp);
    transpose_split<<<dim3(768, 4), 256, 0, stream>>>(
        Wg, 192, 256, 192, 768, WgTh, WgTl, 768L * 192, 256L * 768);

    // st1: PT[t] = NT(WgT_pad[t], x)   [256->192 x 2048], K=768. grid 32x2x4=256
    nt_gemm<0, false, false, false><<<dim3(32, 2, 4), 256, 0, stream>>>(
        WgTh, WgTl, xh, xl, PTh, PTl, nullptr, nullptr, nullptr,
        768, 256, NN, 192, NN, NN, 256L * 768, 0L, 192L * NN, 0);

    // st4: HT[t] = relu(NT(PT[t], G[t]) + bg[t])   [192 x 2048], K=2048. 256 blocks
    nt_gemm<1, true, false, false><<<dim3(32, 2, 4), 256, 0, stream>>>(
        PTh, PTl, Fh, Fl, HTh, HTl, nullptr, bgp, nullptr,
        NN, 192, NN, 192, NN, NN, 192L * NN, NPW, 192L * NN, 256);

    // st5: comb[:, t*192:] = NT(G[t], HT[t])   [2048 x 192], K=2048. 192 blocks
    nt_gemm<0, false, false, false><<<dim3(3, 16, 4), 256, 0, stream>>>(
        Fh, Fl, HTh, HTl, combh, combl, nullptr, nullptr, nullptr,
        NN, NN, 192, NN, 192, 768, NPW, 192L * NN, 192L, 0);

    // st6 prep + out = relu(NT(comb, WfT) + bf)   [2048 x 768], K=768. 192 blocks
    transpose_split<<<dim3(2304, 1), 256, 0, stream>>>(
        Wf, 768, 768, 768, 768, WfTh, WfTl, 0L, 0L);
    nt_gemm<2, true, true, false><<<dim3(12, 16, 1), 256, 0, stream>>>(
        combh, combl, WfTh, WfTl, nullptr, nullptr, out, bf, nullptr,
        768, NN, 768, NN, 768, 768, 0L, 0L, 0L, 0);
}